// Round 1
// baseline (446.915 us; speedup 1.0000x reference)
//
#include <hip/hip_runtime.h>
#include <hip/hip_bf16.h>
#include <stdint.h>
#include <stddef.h>

// ---------------------------------------------------------------------------
// InductiveBuNNLayer: SAGE x2 -> Cayley O (4x4 per node) -> local = O^T x
// -> heat diffusion (10-term Taylor of exp(-L)) applied DIRECTLY to local
// (never materialize the 4096x4096 H) -> @W -> O back-rotate -> relu(+bias)
// n = 4096, E = 131072, feature dim 64 (16 bundles x 4)
// ---------------------------------------------------------------------------

// Pass 1 over edges: SAGE in-degree count (duplicates counted, matches
// segment_sum), heat-kernel out-degree (row) count, dedup'd adjacency bitmap.
__global__ void edge_count_kernel(const int* __restrict__ ei, int E,
                                  float* __restrict__ cnt, float* __restrict__ deg,
                                  unsigned* __restrict__ bitmap, int nwords) {
    int e = blockIdx.x * blockDim.x + threadIdx.x;
    if (e >= E) return;
    int src = ei[e];
    int dst = ei[E + e];
    atomicAdd(&cnt[dst], 1.0f);                 // SAGE mean denominator (dst)
    atomicAdd(&deg[src], 1.0f);                 // heat-kernel degree (row=src)
    atomicOr(&bitmap[(size_t)src * nwords + (dst >> 5)], 1u << (dst & 31));
}

// Self-loops: diagonal bit + dis = (deg+1)^{-1/2}
__global__ void dis_kernel(const float* __restrict__ deg, float* __restrict__ dis,
                           unsigned* __restrict__ bitmap, int n, int nwords) {
    int i = blockIdx.x * blockDim.x + threadIdx.x;
    if (i >= n) return;
    bitmap[(size_t)i * nwords + (i >> 5)] |= (1u << (i & 31)); // only thread i touches row i
    dis[i] = rsqrtf(deg[i] + 1.0f);
}

// Scatter-add feat[src] into msum[dst]; one thread per (edge, feature).
template <int LOGF>
__global__ void scatter_kernel(const int* __restrict__ ei, int E,
                               const float* __restrict__ feat, float* __restrict__ msum) {
    int t = blockIdx.x * blockDim.x + threadIdx.x;
    int e = t >> LOGF;
    if (e >= E) return;
    int f = t & ((1 << LOGF) - 1);
    int src = ei[e];
    int dst = ei[E + e];
    atomicAdd(&msum[((size_t)dst << LOGF) + f], feat[((size_t)src << LOGF) + f]);
}

// h1 = relu(mean1 @ Wl1^T + x @ Wr1^T + b1); one thread per (node, out) out<32
__global__ void sage1_kernel(const float* __restrict__ x, const float* __restrict__ msum1,
                             const float* __restrict__ cnt,
                             const float* __restrict__ Wl, const float* __restrict__ Wr,
                             const float* __restrict__ b,
                             float* __restrict__ h1, int n) {
    int t = blockIdx.x * blockDim.x + threadIdx.x;
    int node = t >> 5;
    if (node >= n) return;
    int o = t & 31;
    float rc = 1.0f / fmaxf(cnt[node], 1.0f);
    const float* ms = msum1 + (size_t)node * 64;
    const float* xr = x + (size_t)node * 64;
    const float* wl = Wl + o * 64;
    const float* wr = Wr + o * 64;
    float am = 0.f, ax = 0.f;
#pragma unroll 8
    for (int f = 0; f < 64; ++f) {
        am += ms[f] * wl[f];
        ax += xr[f] * wr[f];
    }
    h1[(size_t)node * 32 + o] = fmaxf(b[o] + am * rc + ax, 0.f);
}

// Per node: h2 (SAGE2) -> params -> Cayley O=(I-A)^{-1}(I+A) via Gauss-Jordan
// -> local = O^T x_b per bundle. Writes O, termA=local, result=local.
__global__ void node_kernel(const float* __restrict__ x,
                            const float* __restrict__ h1,
                            const float* __restrict__ msum2,
                            const float* __restrict__ cnt,
                            const float* __restrict__ Wl2, const float* __restrict__ Wr2,
                            const float* __restrict__ b2,
                            const float* __restrict__ Wp, const float* __restrict__ bp,
                            float* __restrict__ Og,
                            float* __restrict__ termA,
                            float* __restrict__ result,
                            int n) {
    int i = blockIdx.x * blockDim.x + threadIdx.x;
    if (i >= n) return;
    float rc = 1.0f / fmaxf(cnt[i], 1.0f);
    const float* ms = msum2 + (size_t)i * 32;
    const float* hr = h1 + (size_t)i * 32;
    float h2[16];
#pragma unroll
    for (int o = 0; o < 16; ++o) {
        float am = 0.f, ah = 0.f;
#pragma unroll
        for (int f = 0; f < 32; ++f) {
            am += ms[f] * Wl2[o * 32 + f];
            ah += hr[f] * Wr2[o * 32 + f];
        }
        h2[o] = fmaxf(b2[o] + am * rc + ah, 0.f);
    }
    float p[6];
#pragma unroll
    for (int o = 0; o < 6; ++o) {
        float a = bp[o];
#pragma unroll
        for (int f = 0; f < 16; ++f) a += h2[f] * Wp[o * 16 + f];
        p[o] = a;
    }
    // A skew (upper triangle row-major: (0,1),(0,2),(0,3),(1,2),(1,3),(2,3))
    float A[4][4] = {{0.f,   p[0],  p[1],  p[2]},
                     {-p[0], 0.f,   p[3],  p[4]},
                     {-p[1], -p[3], 0.f,   p[5]},
                     {-p[2], -p[4], -p[5], 0.f}};
    float M[4][4], R[4][4];
#pragma unroll
    for (int r = 0; r < 4; ++r)
#pragma unroll
        for (int c = 0; c < 4; ++c) {
            float id = (r == c) ? 1.f : 0.f;
            M[r][c] = id - A[r][c];
            R[r][c] = id + A[r][c];
        }
    // Gauss-Jordan, no pivoting (M = I - skew, symmetric part = I -> stable)
#pragma unroll
    for (int k = 0; k < 4; ++k) {
        float inv = 1.0f / M[k][k];
#pragma unroll
        for (int c = 0; c < 4; ++c) { M[k][c] *= inv; R[k][c] *= inv; }
#pragma unroll
        for (int r = 0; r < 4; ++r) {
            if (r == k) continue;
            float fk = M[r][k];
#pragma unroll
            for (int c = 0; c < 4; ++c) { M[r][c] -= fk * M[k][c]; R[r][c] -= fk * R[k][c]; }
        }
    }
    float* og = Og + (size_t)i * 16;
#pragma unroll
    for (int r = 0; r < 4; ++r)
#pragma unroll
        for (int c = 0; c < 4; ++c) og[r * 4 + c] = R[r][c];
    // local = O^T x_b  (local[b][c] = sum_j O[j][c] * x[b][j])
    const float* xr = x + (size_t)i * 64;
    float* ta = termA + (size_t)i * 64;
    float* rs = result + (size_t)i * 64;
#pragma unroll
    for (int bb = 0; bb < 16; ++bb) {
        float x0 = xr[bb * 4 + 0], x1 = xr[bb * 4 + 1];
        float x2 = xr[bb * 4 + 2], x3 = xr[bb * 4 + 3];
#pragma unroll
        for (int c = 0; c < 4; ++c) {
            float v = R[0][c] * x0 + R[1][c] * x1 + R[2][c] * x2 + R[3][c] * x3;
            ta[bb * 4 + c] = v;
            rs[bb * 4 + c] = v;
        }
    }
}

// One Taylor step: term_out = coef * (L @ term_in), result += term_out.
// L y = y - dis .* (A (dis .* y)), A = dedup'd adjacency+selfloops (bitmap).
// One wave per row; lane = feature (64).
__global__ void diffuse_kernel(const unsigned* __restrict__ bitmap,
                               const float* __restrict__ dis,
                               const float* __restrict__ term_in,
                               float* __restrict__ term_out,
                               float* __restrict__ result,
                               float coef, int n, int nwords) {
    int gid = blockIdx.x * blockDim.x + threadIdx.x;
    int row = gid >> 6;
    if (row >= n) return;
    int f = gid & 63;
    const unsigned* bm = bitmap + (size_t)row * nwords;
    float acc = 0.f;
    for (int w = 0; w < nwords; ++w) {
        unsigned word = bm[w];   // wave-uniform
        while (word) {
            int b = __ffs(word) - 1;
            word &= word - 1;
            int j = (w << 5) + b;
            acc += dis[j] * term_in[((size_t)j << 6) + f];
        }
    }
    size_t idx = ((size_t)row << 6) + f;
    float val = coef * (term_in[idx] - dis[row] * acc);
    term_out[idx] = val;
    result[idx] += val;
}

// mixed = diffused @ W ; back = O @ mixed_b per bundle ; out = relu(back+bias)
// One wave per row, in place on d_out (each wave reads then writes its row).
__global__ void mix_final_kernel(const float* __restrict__ Og,
                                 const float* __restrict__ W,
                                 const float* __restrict__ bias,
                                 float* __restrict__ out, int n) {
    int gid = blockIdx.x * blockDim.x + threadIdx.x;
    int row = gid >> 6;
    if (row >= n) return;
    int f = gid & 63;
    float d = out[((size_t)row << 6) + f];
    float m = 0.f;
#pragma unroll 8
    for (int k = 0; k < 64; ++k) {
        m += __shfl(d, k, 64) * W[k * 64 + f];
    }
    int b4 = f & ~3;
    int ii = f & 3;
    const float* orow = Og + (size_t)row * 16 + ii * 4;
    float back = orow[0] * __shfl(m, b4 + 0, 64)
               + orow[1] * __shfl(m, b4 + 1, 64)
               + orow[2] * __shfl(m, b4 + 2, 64)
               + orow[3] * __shfl(m, b4 + 3, 64);
    out[((size_t)row << 6) + f] = fmaxf(back + bias[f], 0.f);
}

extern "C" void kernel_launch(void* const* d_in, const int* in_sizes, int n_in,
                              void* d_out, int out_size, void* d_ws, size_t ws_size,
                              hipStream_t stream) {
    const float* x    = (const float*)d_in[0];
    const int*   ei   = (const int*)d_in[1];
    const float* Wl1  = (const float*)d_in[2];
    const float* Wr1  = (const float*)d_in[3];
    const float* b1   = (const float*)d_in[4];
    const float* Wl2  = (const float*)d_in[5];
    const float* Wr2  = (const float*)d_in[6];
    const float* b2   = (const float*)d_in[7];
    const float* Wp   = (const float*)d_in[8];
    const float* bp   = (const float*)d_in[9];
    const float* W    = (const float*)d_in[10];
    const float* bias = (const float*)d_in[11];
    float* out = (float*)d_out;

    int n = in_sizes[0] / 64;
    int E = in_sizes[1] / 2;
    int nwords = (n + 31) >> 5;

    char* ws = (char*)d_ws;
    size_t off = 0;
    unsigned* bitmap = (unsigned*)(ws + off); off += (size_t)n * nwords * 4;
    float* cnt   = (float*)(ws + off); off += (size_t)n * 4;
    float* deg   = (float*)(ws + off); off += (size_t)n * 4;
    float* msum1 = (float*)(ws + off); off += (size_t)n * 64 * 4;
    float* msum2 = (float*)(ws + off); off += (size_t)n * 32 * 4;
    size_t zero_bytes = off;
    float* dis   = (float*)(ws + off); off += (size_t)n * 4;
    float* h1    = (float*)(ws + off); off += (size_t)n * 32 * 4;
    float* Og    = (float*)(ws + off); off += (size_t)n * 16 * 4;
    float* termA = (float*)(ws + off); off += (size_t)n * 64 * 4;
    float* termB = (float*)(ws + off); off += (size_t)n * 64 * 4;

    hipMemsetAsync(d_ws, 0, zero_bytes, stream);

    const int tb = 256;
    edge_count_kernel<<<(E + tb - 1) / tb, tb, 0, stream>>>(ei, E, cnt, deg, bitmap, nwords);
    dis_kernel<<<(n + tb - 1) / tb, tb, 0, stream>>>(deg, dis, bitmap, n, nwords);
    scatter_kernel<6><<<(int)(((size_t)E * 64 + tb - 1) / tb), tb, 0, stream>>>(ei, E, x, msum1);
    sage1_kernel<<<(int)(((size_t)n * 32 + tb - 1) / tb), tb, 0, stream>>>(x, msum1, cnt, Wl1, Wr1, b1, h1, n);
    scatter_kernel<5><<<(int)(((size_t)E * 32 + tb - 1) / tb), tb, 0, stream>>>(ei, E, h1, msum2);
    node_kernel<<<(n + tb - 1) / tb, tb, 0, stream>>>(x, h1, msum2, cnt, Wl2, Wr2, b2, Wp, bp,
                                                      Og, termA, out, n);

    const float t_diff = 1.0f;
    float* ta = termA;
    float* tbuf = termB;
    for (int k = 1; k <= 10; ++k) {
        float coef = -t_diff / (float)k;
        diffuse_kernel<<<(int)(((size_t)n * 64 + tb - 1) / tb), tb, 0, stream>>>(
            bitmap, dis, ta, tbuf, out, coef, n, nwords);
        float* tmp = ta; ta = tbuf; tbuf = tmp;
    }

    mix_final_kernel<<<(int)(((size_t)n * 64 + tb - 1) / tb), tb, 0, stream>>>(Og, W, bias, out, n);
}

// Round 2
// 171.417 us; speedup vs baseline: 2.6072x; 2.6072x over previous
//
#include <hip/hip_runtime.h>
#include <hip/hip_bf16.h>
#include <stdint.h>
#include <stddef.h>

// ---------------------------------------------------------------------------
// InductiveBuNNLayer: SAGE x2 -> Cayley O (4x4/node) -> local = O^T x ->
// heat diffusion (10-term Taylor of exp(-L)) applied directly to local ->
// @W -> O back-rotate -> relu(+bias).  n=4096, E=131072, dim 64 = 16x4.
// Round 2: CSR everywhere (no feature atomics, no serial bitmap scan),
// 8-wide ILP gathers, node work split across 3 full-chip kernels.
// ---------------------------------------------------------------------------

// Per edge: SAGE in-degree (dup-counting), heat out-degree (dup-counting),
// dedup'd adjacency bitmap (matches reference's .at[].set(1.0)).
__global__ void edge_count_kernel(const int* __restrict__ ei, int E,
                                  int* __restrict__ cnt_in, int* __restrict__ deg,
                                  unsigned* __restrict__ bitmap, int nwords) {
    int e = blockIdx.x * blockDim.x + threadIdx.x;
    if (e >= E) return;
    int src = ei[e];
    int dst = ei[E + e];
    atomicAdd(&cnt_in[dst], 1);
    atomicAdd(&deg[src], 1);
    atomicOr(&bitmap[(size_t)src * nwords + (dst >> 5)], 1u << (dst & 31));
}

// Self-loop diag bit; dis = (deg+1)^-1/2 ; rcnt = 1/max(cnt_in,1)
__global__ void dis_kernel(const int* __restrict__ deg, const int* __restrict__ cnt_in,
                           float* __restrict__ dis, float* __restrict__ rcnt,
                           unsigned* __restrict__ bitmap, int n, int nwords) {
    int i = blockIdx.x * blockDim.x + threadIdx.x;
    if (i >= n) return;
    bitmap[(size_t)i * nwords + (i >> 5)] |= (1u << (i & 31));
    dis[i] = rsqrtf((float)deg[i] + 1.0f);
    rcnt[i] = 1.0f / fmaxf((float)cnt_in[i], 1.0f);
}

// Wave per row: popcount of dedup'd row (after diag bit).
__global__ void rowcnt_kernel(const unsigned* __restrict__ bitmap, int* __restrict__ rowcnt,
                              int n, int nwords) {
    int row = blockIdx.x * (blockDim.x >> 6) + (threadIdx.x >> 6);
    if (row >= n) return;
    int lane = threadIdx.x & 63;
    int wpl = (nwords + 63) >> 6;
    const unsigned* bm = bitmap + (size_t)row * nwords;
    int c = 0;
    for (int k = 0; k < wpl; ++k) {
        int w = lane * wpl + k;
        if (w < nwords) c += __popc(bm[w]);
    }
    for (int d = 32; d; d >>= 1) c += __shfl_xor(c, d, 64);
    if (lane == 0) rowcnt[row] = c;
}

// Exclusive scan of two n-length int arrays (block 0: A, block 1: B). n<=4096.
__global__ void scan2_kernel(const int* __restrict__ cntA, int* __restrict__ ptrA,
                             const int* __restrict__ cntB, int* __restrict__ ptrB, int n) {
    const int* cnt = (blockIdx.x == 0) ? cntA : cntB;
    int* ptr = (blockIdx.x == 0) ? ptrA : ptrB;
    __shared__ int lds[1024];
    int t = threadIdx.x;
    int per = (n + 1023) >> 10;
    int base = t * per;
    int s = 0;
    for (int k = 0; k < per; ++k) if (base + k < n) s += cnt[base + k];
    lds[t] = s;
    __syncthreads();
    for (int d = 1; d < 1024; d <<= 1) {
        int v = (t >= d) ? lds[t - d] : 0;
        __syncthreads();
        lds[t] += v;
        __syncthreads();
    }
    int run = (t == 0) ? 0 : lds[t - 1];
    for (int k = 0; k < per; ++k)
        if (base + k < n) { ptr[base + k] = run; run += cnt[base + k]; }
    if (t == 1023) ptr[n] = lds[1023];
}

// Fill dst-CSR (duplicates kept; slot order nondeterministic -> fp-noise only).
__global__ void fill_in_kernel(const int* __restrict__ ei, int E,
                               const int* __restrict__ in_ptr, int* __restrict__ pos,
                               int* __restrict__ in_cols) {
    int e = blockIdx.x * blockDim.x + threadIdx.x;
    if (e >= E) return;
    int src = ei[e];
    int dst = ei[E + e];
    int slot = atomicAdd(&pos[dst], 1);
    in_cols[in_ptr[dst] + slot] = src;
}

// Wave per row: bitmap -> CSR (ascending cols, deterministic), w = dis_i*dis_j.
__global__ void extract_kernel(const unsigned* __restrict__ bitmap,
                               const int* __restrict__ row_ptr,
                               const float* __restrict__ dis,
                               int2* __restrict__ nbr, int n, int nwords) {
    int row = blockIdx.x * (blockDim.x >> 6) + (threadIdx.x >> 6);
    if (row >= n) return;
    int lane = threadIdx.x & 63;
    int wpl = (nwords + 63) >> 6;
    const unsigned* bm = bitmap + (size_t)row * nwords;
    int c = 0;
    for (int k = 0; k < wpl; ++k) {
        int w = lane * wpl + k;
        if (w < nwords) c += __popc(bm[w]);
    }
    int incl = c;
    for (int d = 1; d < 64; d <<= 1) {
        int v = __shfl_up(incl, d, 64);
        if (lane >= d) incl += v;
    }
    int pos = row_ptr[row] + incl - c;
    float di = dis[row];
    for (int k = 0; k < wpl; ++k) {
        int w = lane * wpl + k;
        if (w >= nwords) break;
        unsigned word = bm[w];
        while (word) {
            int b = __ffs(word) - 1;
            word &= word - 1;
            int j = (w << 5) + b;
            int2 p;
            p.x = j;
            p.y = __float_as_int(di * dis[j]);
            nbr[pos++] = p;
        }
    }
}

// Wave per node, lane = feature (64): msum1 = sum over in-edges of x[src].
__global__ void gather1_kernel(const int* __restrict__ in_ptr, const int* __restrict__ in_cols,
                               const float* __restrict__ x, float* __restrict__ msum, int n) {
    int row = blockIdx.x * (blockDim.x >> 6) + (threadIdx.x >> 6);
    if (row >= n) return;
    int f = threadIdx.x & 63;
    int s = in_ptr[row], e = in_ptr[row + 1];
    float acc = 0.f;
    int i = s;
    for (; i + 8 <= e; i += 8) {
        int c0 = in_cols[i], c1 = in_cols[i + 1], c2 = in_cols[i + 2], c3 = in_cols[i + 3];
        int c4 = in_cols[i + 4], c5 = in_cols[i + 5], c6 = in_cols[i + 6], c7 = in_cols[i + 7];
        float t0 = x[((size_t)c0 << 6) + f], t1 = x[((size_t)c1 << 6) + f];
        float t2 = x[((size_t)c2 << 6) + f], t3 = x[((size_t)c3 << 6) + f];
        float t4 = x[((size_t)c4 << 6) + f], t5 = x[((size_t)c5 << 6) + f];
        float t6 = x[((size_t)c6 << 6) + f], t7 = x[((size_t)c7 << 6) + f];
        acc += ((t0 + t1) + (t2 + t3)) + ((t4 + t5) + (t6 + t7));
    }
    for (; i < e; ++i) acc += x[((size_t)in_cols[i] << 6) + f];
    msum[((size_t)row << 6) + f] = acc;
}

// Half-wave per node, lane = feature (32): msum2 = sum of h1[src].
__global__ void gather2_kernel(const int* __restrict__ in_ptr, const int* __restrict__ in_cols,
                               const float* __restrict__ h1, float* __restrict__ msum, int n) {
    int row = blockIdx.x * (blockDim.x >> 5) + (threadIdx.x >> 5);
    if (row >= n) return;
    int f = threadIdx.x & 31;
    int s = in_ptr[row], e = in_ptr[row + 1];
    float acc = 0.f;
    int i = s;
    for (; i + 8 <= e; i += 8) {
        int c0 = in_cols[i], c1 = in_cols[i + 1], c2 = in_cols[i + 2], c3 = in_cols[i + 3];
        int c4 = in_cols[i + 4], c5 = in_cols[i + 5], c6 = in_cols[i + 6], c7 = in_cols[i + 7];
        float t0 = h1[((size_t)c0 << 5) + f], t1 = h1[((size_t)c1 << 5) + f];
        float t2 = h1[((size_t)c2 << 5) + f], t3 = h1[((size_t)c3 << 5) + f];
        float t4 = h1[((size_t)c4 << 5) + f], t5 = h1[((size_t)c5 << 5) + f];
        float t6 = h1[((size_t)c6 << 5) + f], t7 = h1[((size_t)c7 << 5) + f];
        acc += ((t0 + t1) + (t2 + t3)) + ((t4 + t5) + (t6 + t7));
    }
    for (; i < e; ++i) acc += h1[((size_t)in_cols[i] << 5) + f];
    msum[((size_t)row << 5) + f] = acc;
}

// h1 = relu(mean1 @ Wl1^T + x @ Wr1^T + b1); thread per (node, o<32).
__global__ void sage1_kernel(const float* __restrict__ x, const float* __restrict__ msum1,
                             const float* __restrict__ rcnt,
                             const float* __restrict__ Wl, const float* __restrict__ Wr,
                             const float* __restrict__ b,
                             float* __restrict__ h1, int n) {
    int t = blockIdx.x * blockDim.x + threadIdx.x;
    int node = t >> 5;
    if (node >= n) return;
    int o = t & 31;
    float rc = rcnt[node];
    const float* ms = msum1 + (size_t)node * 64;
    const float* xr = x + (size_t)node * 64;
    const float* wl = Wl + o * 64;
    const float* wr = Wr + o * 64;
    float am = 0.f, ax = 0.f;
#pragma unroll 8
    for (int f = 0; f < 64; ++f) {
        am += ms[f] * wl[f];
        ax += xr[f] * wr[f];
    }
    h1[(size_t)node * 32 + o] = fmaxf(b[o] + am * rc + ax, 0.f);
}

// h2 = relu(mean2 @ Wl2^T + h1 @ Wr2^T + b2); thread per (node, o<16).
__global__ void sage2_kernel(const float* __restrict__ h1, const float* __restrict__ msum2,
                             const float* __restrict__ rcnt,
                             const float* __restrict__ Wl2, const float* __restrict__ Wr2,
                             const float* __restrict__ b2,
                             float* __restrict__ h2, int n) {
    int t = blockIdx.x * blockDim.x + threadIdx.x;
    int node = t >> 4;
    if (node >= n) return;
    int o = t & 15;
    float rc = rcnt[node];
    const float* ms = msum2 + (size_t)node * 32;
    const float* hr = h1 + (size_t)node * 32;
    const float* wl = Wl2 + o * 32;
    const float* wr = Wr2 + o * 32;
    float am = 0.f, ah = 0.f;
#pragma unroll 8
    for (int f = 0; f < 32; ++f) {
        am += ms[f] * wl[f];
        ah += hr[f] * wr[f];
    }
    h2[(size_t)node * 16 + o] = fmaxf(b2[o] + am * rc + ah, 0.f);
}

// Per node: params -> Cayley O = (I-A)^{-1}(I+A) via pivot-free Gauss-Jordan.
__global__ void cayley_kernel(const float* __restrict__ h2,
                              const float* __restrict__ Wp, const float* __restrict__ bp,
                              float* __restrict__ Og, int n) {
    int i = blockIdx.x * blockDim.x + threadIdx.x;
    if (i >= n) return;
    const float* hv = h2 + (size_t)i * 16;
    float p[6];
#pragma unroll
    for (int o = 0; o < 6; ++o) {
        float a = bp[o];
#pragma unroll
        for (int f = 0; f < 16; ++f) a += hv[f] * Wp[o * 16 + f];
        p[o] = a;
    }
    float A[4][4] = {{0.f,   p[0],  p[1],  p[2]},
                     {-p[0], 0.f,   p[3],  p[4]},
                     {-p[1], -p[3], 0.f,   p[5]},
                     {-p[2], -p[4], -p[5], 0.f}};
    float M[4][4], R[4][4];
#pragma unroll
    for (int r = 0; r < 4; ++r)
#pragma unroll
        for (int c = 0; c < 4; ++c) {
            float id = (r == c) ? 1.f : 0.f;
            M[r][c] = id - A[r][c];
            R[r][c] = id + A[r][c];
        }
#pragma unroll
    for (int k = 0; k < 4; ++k) {
        float inv = 1.0f / M[k][k];
#pragma unroll
        for (int c = 0; c < 4; ++c) { M[k][c] *= inv; R[k][c] *= inv; }
#pragma unroll
        for (int r = 0; r < 4; ++r) {
            if (r == k) continue;
            float fk = M[r][k];
#pragma unroll
            for (int c = 0; c < 4; ++c) { M[r][c] -= fk * M[k][c]; R[r][c] -= fk * R[k][c]; }
        }
    }
    float* og = Og + (size_t)i * 16;
#pragma unroll
    for (int r = 0; r < 4; ++r)
#pragma unroll
        for (int c = 0; c < 4; ++c) og[r * 4 + c] = R[r][c];
}

// Thread per (node, bundle): local = O^T x_b ; writes termA and result(out).
__global__ void rotate_kernel(const float* __restrict__ x, const float* __restrict__ Og,
                              float* __restrict__ termA, float* __restrict__ out, int n) {
    int t = blockIdx.x * blockDim.x + threadIdx.x;
    int node = t >> 4;
    if (node >= n) return;
    int b = t & 15;
    const float* og = Og + (size_t)node * 16;
    float o[16];
#pragma unroll
    for (int k = 0; k < 16; ++k) o[k] = og[k];
    float4 xv = *(const float4*)(x + (size_t)node * 64 + b * 4);
    float4 r;
    r.x = o[0] * xv.x + o[4] * xv.y + o[8]  * xv.z + o[12] * xv.w;
    r.y = o[1] * xv.x + o[5] * xv.y + o[9]  * xv.z + o[13] * xv.w;
    r.z = o[2] * xv.x + o[6] * xv.y + o[10] * xv.z + o[14] * xv.w;
    r.w = o[3] * xv.x + o[7] * xv.y + o[11] * xv.z + o[15] * xv.w;
    *(float4*)(termA + (size_t)node * 64 + b * 4) = r;
    *(float4*)(out + (size_t)node * 64 + b * 4) = r;
}

// One Taylor step via CSR: val = coef*(y_i - sum_e w_e * y_col(e)); result += val.
// Wave per row, lane = feature; 8-wide ILP on the gather.
__global__ void diffuse_kernel(const int* __restrict__ row_ptr,
                               const int2* __restrict__ nbr,
                               const float* __restrict__ term_in,
                               float* __restrict__ term_out,
                               float* __restrict__ result,
                               float coef, int n) {
    int row = blockIdx.x * (blockDim.x >> 6) + (threadIdx.x >> 6);
    if (row >= n) return;
    int f = threadIdx.x & 63;
    int s = row_ptr[row], e = row_ptr[row + 1];
    float acc = 0.f;
    int i = s;
    for (; i + 8 <= e; i += 8) {
        int2 p0 = nbr[i], p1 = nbr[i + 1], p2 = nbr[i + 2], p3 = nbr[i + 3];
        int2 p4 = nbr[i + 4], p5 = nbr[i + 5], p6 = nbr[i + 6], p7 = nbr[i + 7];
        float t0 = term_in[((size_t)p0.x << 6) + f], t1 = term_in[((size_t)p1.x << 6) + f];
        float t2 = term_in[((size_t)p2.x << 6) + f], t3 = term_in[((size_t)p3.x << 6) + f];
        float t4 = term_in[((size_t)p4.x << 6) + f], t5 = term_in[((size_t)p5.x << 6) + f];
        float t6 = term_in[((size_t)p6.x << 6) + f], t7 = term_in[((size_t)p7.x << 6) + f];
        acc = fmaf(__int_as_float(p0.y), t0, acc);
        acc = fmaf(__int_as_float(p1.y), t1, acc);
        acc = fmaf(__int_as_float(p2.y), t2, acc);
        acc = fmaf(__int_as_float(p3.y), t3, acc);
        acc = fmaf(__int_as_float(p4.y), t4, acc);
        acc = fmaf(__int_as_float(p5.y), t5, acc);
        acc = fmaf(__int_as_float(p6.y), t6, acc);
        acc = fmaf(__int_as_float(p7.y), t7, acc);
    }
    for (; i < e; ++i) {
        int2 p = nbr[i];
        acc = fmaf(__int_as_float(p.y), term_in[((size_t)p.x << 6) + f], acc);
    }
    size_t idx = ((size_t)row << 6) + f;
    float val = coef * (term_in[idx] - acc);
    term_out[idx] = val;
    result[idx] += val;
}

// mixed = diffused @ W ; back = O @ mixed_b ; out = relu(back + bias). In place.
__global__ void mix_final_kernel(const float* __restrict__ Og,
                                 const float* __restrict__ W,
                                 const float* __restrict__ bias,
                                 float* __restrict__ out, int n) {
    int gid = blockIdx.x * blockDim.x + threadIdx.x;
    int row = gid >> 6;
    if (row >= n) return;
    int f = gid & 63;
    float d = out[((size_t)row << 6) + f];
    float m = 0.f;
#pragma unroll 8
    for (int k = 0; k < 64; ++k) {
        m += __shfl(d, k, 64) * W[k * 64 + f];
    }
    int b4 = f & ~3;
    int ii = f & 3;
    const float* orow = Og + (size_t)row * 16 + ii * 4;
    float back = orow[0] * __shfl(m, b4 + 0, 64)
               + orow[1] * __shfl(m, b4 + 1, 64)
               + orow[2] * __shfl(m, b4 + 2, 64)
               + orow[3] * __shfl(m, b4 + 3, 64);
    out[((size_t)row << 6) + f] = fmaxf(back + bias[f], 0.f);
}

extern "C" void kernel_launch(void* const* d_in, const int* in_sizes, int n_in,
                              void* d_out, int out_size, void* d_ws, size_t ws_size,
                              hipStream_t stream) {
    const float* x    = (const float*)d_in[0];
    const int*   ei   = (const int*)d_in[1];
    const float* Wl1  = (const float*)d_in[2];
    const float* Wr1  = (const float*)d_in[3];
    const float* b1   = (const float*)d_in[4];
    const float* Wl2  = (const float*)d_in[5];
    const float* Wr2  = (const float*)d_in[6];
    const float* b2   = (const float*)d_in[7];
    const float* Wp   = (const float*)d_in[8];
    const float* bp   = (const float*)d_in[9];
    const float* W    = (const float*)d_in[10];
    const float* bias = (const float*)d_in[11];
    float* out = (float*)d_out;

    int n = in_sizes[0] / 64;
    int E = in_sizes[1] / 2;
    int nwords = (n + 31) >> 5;

    char* ws = (char*)d_ws;
    size_t off = 0;
    unsigned* bitmap = (unsigned*)(ws + off); off += (size_t)n * nwords * 4;
    int* cnt_in = (int*)(ws + off); off += (size_t)n * 4;
    int* deg    = (int*)(ws + off); off += (size_t)n * 4;
    int* pos    = (int*)(ws + off); off += (size_t)n * 4;
    size_t zero_bytes = off;
    int2* nbr   = (int2*)(ws + off); off += (size_t)(E + n) * 8;
    int* in_ptr  = (int*)(ws + off); off += (size_t)(n + 1) * 4;
    int* row_ptr = (int*)(ws + off); off += (size_t)(n + 1) * 4;
    int* rowcnt  = (int*)(ws + off); off += (size_t)n * 4;
    int* in_cols = (int*)(ws + off); off += (size_t)E * 4;
    float* dis   = (float*)(ws + off); off += (size_t)n * 4;
    float* rcnt  = (float*)(ws + off); off += (size_t)n * 4;
    float* msum1 = (float*)(ws + off); off += (size_t)n * 64 * 4;
    float* h1    = (float*)(ws + off); off += (size_t)n * 32 * 4;
    float* msum2 = (float*)(ws + off); off += (size_t)n * 32 * 4;
    float* h2    = (float*)(ws + off); off += (size_t)n * 16 * 4;
    float* Og    = (float*)(ws + off); off += (size_t)n * 16 * 4;
    float* termA = (float*)(ws + off); off += (size_t)n * 64 * 4;
    float* termB = (float*)(ws + off); off += (size_t)n * 64 * 4;

    hipMemsetAsync(d_ws, 0, zero_bytes, stream);

    const int tb = 256;
    edge_count_kernel<<<(E + tb - 1) / tb, tb, 0, stream>>>(ei, E, cnt_in, deg, bitmap, nwords);
    dis_kernel<<<(n + tb - 1) / tb, tb, 0, stream>>>(deg, cnt_in, dis, rcnt, bitmap, n, nwords);
    rowcnt_kernel<<<(n + 3) / 4, tb, 0, stream>>>(bitmap, rowcnt, n, nwords);
    scan2_kernel<<<2, 1024, 0, stream>>>(cnt_in, in_ptr, rowcnt, row_ptr, n);
    fill_in_kernel<<<(E + tb - 1) / tb, tb, 0, stream>>>(ei, E, in_ptr, pos, in_cols);
    extract_kernel<<<(n + 3) / 4, tb, 0, stream>>>(bitmap, row_ptr, dis, nbr, n, nwords);

    gather1_kernel<<<(n + 3) / 4, tb, 0, stream>>>(in_ptr, in_cols, x, msum1, n);
    sage1_kernel<<<(int)(((size_t)n * 32 + tb - 1) / tb), tb, 0, stream>>>(x, msum1, rcnt, Wl1, Wr1, b1, h1, n);
    gather2_kernel<<<(n + 7) / 8, tb, 0, stream>>>(in_ptr, in_cols, h1, msum2, n);
    sage2_kernel<<<(int)(((size_t)n * 16 + tb - 1) / tb), tb, 0, stream>>>(h1, msum2, rcnt, Wl2, Wr2, b2, h2, n);
    cayley_kernel<<<(n + 63) / 64, 64, 0, stream>>>(h2, Wp, bp, Og, n);
    rotate_kernel<<<(int)(((size_t)n * 16 + tb - 1) / tb), tb, 0, stream>>>(x, Og, termA, out, n);

    const float t_diff = 1.0f;
    float* ta = termA;
    float* tbuf = termB;
    for (int k = 1; k <= 10; ++k) {
        float coef = -t_diff / (float)k;
        diffuse_kernel<<<(n + 3) / 4, tb, 0, stream>>>(row_ptr, nbr, ta, tbuf, out, coef, n);
        float* tmp = ta; ta = tbuf; tbuf = tmp;
    }

    mix_final_kernel<<<(int)(((size_t)n * 64 + tb - 1) / tb), tb, 0, stream>>>(Og, W, bias, out, n);
}